// Round 7
// baseline (37.556 us; speedup 1.0000x reference)
//
#include <hip/hip_runtime.h>
#include <math.h>

#define LC 8
#define FAC 120
#define KS 5
#define KK 25
#define IWID 64
#define NH 60
#define SS 3600
#define PIXB 128         // pixels per block
#define NBLK 450         // 57600/128 ; co-resident: <= 512 slots at 2 blocks/CU
#define PADW 40          // shorts per pat row (80B stride -> no bank conflicts)

using bf16x8 = __attribute__((ext_vector_type(8))) short;
using f32x4  = __attribute__((ext_vector_type(4))) float;

// ws layout: [0,65536) M_hi [8][128][32] bf16 ; [65536,131072) M_lo ;
//            [131072,131104) msq[8] f32 ; [131104,131120) flags[4] u32
#define MS_LO_OFF 32768   // in shorts
#define MSQ_BYTE  131072
#define FLAG_BYTE 131104
#define MAGIC0 0x4D41474Bu

__device__ __forceinline__ short f2bf(float v) {
  unsigned u = __builtin_bit_cast(unsigned, v);
  unsigned r = u + 0x7FFFu + ((u >> 16) & 1u);   // RNE
  return (short)(r >> 16);
}
__device__ __forceinline__ float bf2f(short h) {
  unsigned u = ((unsigned)(unsigned short)h) << 16;
  return __builtin_bit_cast(float, u);
}

// fused k1+k2: blocks 0..3 build M (idempotent, flag-gated); all 450 blocks
// gather patches, spin on flags, then MFMA cross-term -> exp(-feature).
__global__ __launch_bounds__(256, 2) void k12_feat(const float* __restrict__ x,
                                                   const float* __restrict__ kern,
                                                   void* __restrict__ wsv,
                                                   float* __restrict__ out) {
  __shared__ short pat_hi[PIXB][PADW];
  __shared__ short pat_lo[PIXB][PADW];
  __shared__ float xsq_s[PIXB];
  short* MH = (short*)wsv;
  short* ML = MH + MS_LO_OFF;
  float* MSQ = (float*)((char*)wsv + MSQ_BYTE);
  unsigned* flags = (unsigned*)((char*)wsv + FLAG_BYTE);

  const int tid = threadIdx.x;
  const int bid = blockIdx.x;
  const int w = tid >> 6;
  const int lane = tid & 63;
  const int u0 = bid * PIXB;

  // ---- producer: blocks 0..3 build the split M table (1024 (l,f) slots) ----
  if (bid < 4) {
    const int gid = bid * 256 + tid;     // l*128 + f
    const int l = gid >> 7;
    const int f = gid & 127;
    short* h = MH + gid * 32;
    short* lo = ML + gid * 32;
    if (f < FAC) {
      int avail[KS] = {0, 1, 2, 3, 4};
      int perm[KS];
      int rem = f;
      const int divs[4] = {24, 6, 2, 1};
      for (int i = 0; i < 4; ++i) {
        const int d = rem / divs[i];
        rem -= d * divs[i];
        perm[i] = avail[d];
        for (int j = d; j < 4 - i; ++j) avail[j] = avail[j + 1];
      }
      perm[4] = avail[0];
      const float* Kl = kern + l * KK;
      #pragma unroll
      for (int a = 0; a < KS; ++a)
        #pragma unroll
        for (int d = 0; d < KS; ++d) {
          const float v = Kl[perm[a] * KS + perm[d]];
          const short hs = f2bf(v);
          h[a * KS + d] = hs;
          lo[a * KS + d] = f2bf(v - bf2f(hs));
        }
      #pragma unroll
      for (int q = KK; q < 32; ++q) { h[q] = 0; lo[q] = 0; }
      if (f == 0) {
        float s = 0.f;
        #pragma unroll
        for (int q = 0; q < KK; ++q) s = fmaf(Kl[q], Kl[q], s);
        MSQ[l] = s;
      }
    } else {
      #pragma unroll
      for (int q = 0; q < 32; ++q) { h[q] = 0; lo[q] = 0; }
    }
    __syncthreads();
    if (tid == 0)
      __hip_atomic_store(&flags[bid], MAGIC0 + (unsigned)bid,
                         __ATOMIC_RELEASE, __HIP_MEMORY_SCOPE_AGENT);
  }
  if (bid == 4) {   // kernel copy to output tail (independent of M)
    for (int i = tid; i < LC * KK; i += 256) out[460800 + i] = kern[i];
  }

  // ---- patch gather + fp32 xsq + hi/lo split (overlaps producer) ----
  if (tid < PIXB) {
    const int u = u0 + tid;
    const int plane = u / SS;
    const int s = u - plane * SS;
    const int ih = s / NH;
    const int iw = s - ih * NH;
    const float* xb = x + plane * (IWID * IWID) + ih * IWID + iw;
    float p[KK];
    #pragma unroll
    for (int a = 0; a < KS; ++a)
      #pragma unroll
      for (int d = 0; d < KS; ++d)
        p[a * KS + d] = xb[a * IWID + d];
    float xs = 0.f;
    #pragma unroll
    for (int q = 0; q < KK; ++q) xs = fmaf(p[q], p[q], xs);
    xsq_s[tid] = xs;
    bf16x8 ph[4], pl[4];
    #pragma unroll
    for (int c = 0; c < 4; ++c) { ph[c] = (bf16x8)(short)0; pl[c] = (bf16x8)(short)0; }
    #pragma unroll
    for (int q = 0; q < KK; ++q) {
      const short hs = f2bf(p[q]);
      ph[q >> 3][q & 7] = hs;
      pl[q >> 3][q & 7] = f2bf(p[q] - bf2f(hs));
    }
    #pragma unroll
    for (int c = 0; c < 4; ++c) {
      *(bf16x8*)&pat_hi[tid][c * 8] = ph[c];
      *(bf16x8*)&pat_lo[tid][c * 8] = pl[c];
    }
  }
  __syncthreads();

  const int pixhalf = w & 1;
  const int l0 = (w >> 1) * 4;

  // B fragments + xsq in registers (reused across this wave's 4 l's)
  bf16x8 BH[4], BL[4];
  float xs4[4];
  #pragma unroll
  for (int j = 0; j < 4; ++j) {
    const int prow = (pixhalf << 6) + (j << 4) + (lane & 15);
    BH[j] = *(const bf16x8*)&pat_hi[prow][(lane >> 4) * 8];
    BL[j] = *(const bf16x8*)&pat_lo[prow][(lane >> 4) * 8];
    xs4[j] = xsq_s[prow];
  }

  // ---- consumer gate: wait for all 4 M-quarters (acquire, device scope) ----
  if (tid == 0) {
    #pragma unroll 1
    for (int i = 0; i < 4; ++i)
      while (__hip_atomic_load(&flags[i], __ATOMIC_ACQUIRE,
                               __HIP_MEMORY_SCOPE_AGENT) != MAGIC0 + (unsigned)i) {}
  }
  __syncthreads();

  const short* abase = (const short*)MH + ((lane & 15) * 32) + ((lane >> 4) * 8);
  const f32x4 Z = {0.f, 0.f, 0.f, 0.f};

  #pragma unroll 1
  for (int li = 0; li < 4; ++li) {
    const int l = l0 + li;
    const short* bh = abase + l * 4096;
    bf16x8 Ah[8], Al[8];
    #pragma unroll
    for (int t = 0; t < 8; ++t) {
      Ah[t] = *(const bf16x8*)(bh + t * 512);
      Al[t] = *(const bf16x8*)(bh + t * 512 + MS_LO_OFF);
    }
    const float ml = MSQ[l];
    float mx[4];
    #pragma unroll
    for (int j = 0; j < 4; ++j) mx[j] = -INFINITY;
    #pragma unroll
    for (int t = 0; t < 8; ++t) {
      #pragma unroll
      for (int j = 0; j < 4; ++j) {
        f32x4 C = __builtin_amdgcn_mfma_f32_16x16x32_bf16(Ah[t], BH[j], Z, 0, 0, 0);
        C = __builtin_amdgcn_mfma_f32_16x16x32_bf16(Al[t], BH[j], C, 0, 0, 0);
        C = __builtin_amdgcn_mfma_f32_16x16x32_bf16(Ah[t], BL[j], C, 0, 0, 0);
        if (t < 7) {
          mx[j] = fmaxf(mx[j], fmaxf(fmaxf(C[0], C[1]), fmaxf(C[2], C[3])));
        } else if (lane < 32) {   // f-rows 112..119 valid, 120..127 are pad
          mx[j] = fmaxf(mx[j], fmaxf(fmaxf(C[0], C[1]), fmaxf(C[2], C[3])));
        }
      }
    }
    #pragma unroll
    for (int j = 0; j < 4; ++j) {
      float m = mx[j];
      m = fmaxf(m, __shfl_xor(m, 16));
      m = fmaxf(m, __shfl_xor(m, 32));
      if (lane < 16) {
        // e = exp(-feature); feature = ml + xsq - 2*max >= 0 so e <= ~1
        const float e = expf(2.f * m - ml - xs4[j]);
        const int up = u0 + (pixhalf << 6) + (j << 4) + lane;
        const int pl = up / SS;
        const int sx = up - pl * SS;
        out[(((pl >> 1) * 16) + ((pl & 1) * 8) + l) * SS + sx] = e;
      }
    }
  }
}

// k3: per-(b,c)-row sum + normalize (single pass; data already exp'd).
__global__ __launch_bounds__(1024) void k3_norm(float* __restrict__ data) {
  const int row = blockIdx.x;   // b*16 + c
  float* __restrict__ dr = data + row * SS;
  const int tid = threadIdx.x;
  float v[4];
  float sum = 0.f;
  #pragma unroll
  for (int i = 0; i < 4; ++i) {
    const int s = tid + i * 1024;
    const float f = (s < SS) ? dr[s] : 0.f;
    v[i] = f;
    sum += f;
  }
  #pragma unroll
  for (int off = 32; off >= 1; off >>= 1) sum += __shfl_xor(sum, off);
  __shared__ float red[16];
  if ((tid & 63) == 0) red[tid >> 6] = sum;
  __syncthreads();
  float tot = 0.f;
  #pragma unroll
  for (int i = 0; i < 16; ++i) tot += red[i];
  const float inv = 1.0f / tot;
  #pragma unroll
  for (int i = 0; i < 4; ++i) {
    const int s = tid + i * 1024;
    if (s < SS) dr[s] = v[i] * inv;
  }
}

extern "C" void kernel_launch(void* const* d_in, const int* in_sizes, int n_in,
                              void* d_out, int out_size, void* d_ws, size_t ws_size,
                              hipStream_t stream) {
  const float* x = (const float*)d_in[0];
  const float* kern = (const float*)d_in[1];
  float* out = (float*)d_out;
  hipLaunchKernelGGL(k12_feat, dim3(NBLK), dim3(256), 0, stream, x, kern, d_ws, out);
  hipLaunchKernelGGL(k3_norm, dim3(128), dim3(1024), 0, stream, out);
}

// Round 8
// 27.373 us; speedup vs baseline: 1.3720x; 1.3720x over previous
//
#include <hip/hip_runtime.h>
#include <math.h>

#define LC 8
#define FAC 120
#define KS 5
#define KK 25
#define IWID 64
#define NH 60
#define SS 3600
#define PIXB 128
#define NBLK 1800        // (57600/128 px-blocks) * 4 l-pairs; no inter-block deps

using bf16x8 = __attribute__((ext_vector_type(8))) short;
using f32x4  = __attribute__((ext_vector_type(4))) float;

__device__ __forceinline__ short f2bf(float v) {
  unsigned u = __builtin_bit_cast(unsigned, v);
  unsigned r = u + 0x7FFFu + ((u >> 16) & 1u);   // RNE
  return (short)(r >> 16);
}
__device__ __forceinline__ float bf2f(short h) {
  unsigned u = ((unsigned)(unsigned short)h) << 16;
  return __builtin_bit_cast(float, u);
}

// Fused: each block builds its own 2-l M slice in LDS (no global ws, no sync
// with other blocks), then MFMA cross-term -> exp(-feature).
__global__ __launch_bounds__(256, 3) void k12_feat(const float* __restrict__ x,
                                                   const float* __restrict__ kern,
                                                   float* __restrict__ out) {
  __shared__ short pat_hi[PIXB][32];
  __shared__ short pat_lo[PIXB][32];
  __shared__ short Mh[2][128][32];   // [l-of-pair][f(pad 120..127=0)][q(pad 25..31=0)]
  __shared__ short Ml[2][128][32];
  __shared__ float xsq_s[PIXB];
  __shared__ unsigned Kpk[64];       // [l][q] packed (hi<<16)|lo bf16 split of K
  __shared__ float msqs[2];

  const int tid = threadIdx.x;
  const int bid = blockIdx.x;
  const int pxblk = bid >> 2;        // 0..449
  const int l0 = (bid & 3) * 2;      // l-pair base
  const int u0 = pxblk * PIXB;
  const int w = tid >> 6;
  const int lane = tid & 63;

  if (bid == 0 && tid < LC * KK) out[460800 + tid] = kern[tid];  // tuple tail

  // threads 0..127: issue patch loads; threads 128..191: stage packed K split
  float p[KK];
  if (tid < PIXB) {
    const int u = u0 + tid;
    const int plane = u / SS;
    const int s = u - plane * SS;
    const int ih = s / NH;
    const int iw = s - ih * NH;
    const float* xb = x + plane * (IWID * IWID) + ih * IWID + iw;
    #pragma unroll
    for (int a = 0; a < KS; ++a)
      #pragma unroll
      for (int d = 0; d < KS; ++d)
        p[a * KS + d] = xb[a * IWID + d];
  } else if (tid < 192) {
    const int ll = (tid - 128) >> 5;
    const int q = (tid - 128) & 31;
    unsigned pk = 0;
    if (q < KK) {
      const float v = kern[(l0 + ll) * KK + q];
      const short hs = f2bf(v);
      const short ls = f2bf(v - bf2f(hs));
      pk = ((unsigned)(unsigned short)hs << 16) | (unsigned)(unsigned short)ls;
    }
    Kpk[tid - 128] = pk;
  }
  __syncthreads();   // Kpk visible

  if (tid >= 128) {
    // build M row f (= tid-128) for BOTH l's of the pair (one perm decode)
    const int f = tid - 128;
    bf16x8 H0[4], L0[4], H1[4], L1[4];
    #pragma unroll
    for (int c = 0; c < 4; ++c) {
      H0[c] = (bf16x8)(short)0; L0[c] = (bf16x8)(short)0;
      H1[c] = (bf16x8)(short)0; L1[c] = (bf16x8)(short)0;
    }
    if (f < FAC) {
      int avail[KS] = {0, 1, 2, 3, 4};
      int perm[KS];
      int rem = f;
      const int divs[4] = {24, 6, 2, 1};
      for (int i = 0; i < 4; ++i) {
        const int d = rem / divs[i];
        rem -= d * divs[i];
        perm[i] = avail[d];
        for (int j = d; j < 4 - i; ++j) avail[j] = avail[j + 1];
      }
      perm[4] = avail[0];
      #pragma unroll
      for (int a = 0; a < KS; ++a)
        #pragma unroll
        for (int d = 0; d < KS; ++d) {
          const int q = a * KS + d;
          const int idx = perm[a] * KS + perm[d];   // per-lane LDS gather index
          const unsigned k0 = Kpk[idx];
          const unsigned k1 = Kpk[32 + idx];
          H0[q >> 3][q & 7] = (short)(k0 >> 16);
          L0[q >> 3][q & 7] = (short)(k0 & 0xFFFFu);
          H1[q >> 3][q & 7] = (short)(k1 >> 16);
          L1[q >> 3][q & 7] = (short)(k1 & 0xFFFFu);
        }
    }
    #pragma unroll
    for (int c = 0; c < 4; ++c) {
      *(bf16x8*)&Mh[0][f][c * 8] = H0[c];
      *(bf16x8*)&Ml[0][f][c * 8] = L0[c];
      *(bf16x8*)&Mh[1][f][c * 8] = H1[c];
      *(bf16x8*)&Ml[1][f][c * 8] = L1[c];
    }
    if (f < 2) {   // exact f32 msq
      const float* Kl = kern + (l0 + f) * KK;
      float s = 0.f;
      #pragma unroll
      for (int q = 0; q < KK; ++q) s = fmaf(Kl[q], Kl[q], s);
      msqs[f] = s;
    }
  } else {
    // patch threads: xsq + hi/lo split + vectorized pat writes
    float xs = 0.f;
    #pragma unroll
    for (int q = 0; q < KK; ++q) xs = fmaf(p[q], p[q], xs);
    xsq_s[tid] = xs;
    bf16x8 ph[4], pl[4];
    #pragma unroll
    for (int c = 0; c < 4; ++c) { ph[c] = (bf16x8)(short)0; pl[c] = (bf16x8)(short)0; }
    #pragma unroll
    for (int q = 0; q < KK; ++q) {
      const short hs = f2bf(p[q]);
      ph[q >> 3][q & 7] = hs;
      pl[q >> 3][q & 7] = f2bf(p[q] - bf2f(hs));
    }
    #pragma unroll
    for (int c = 0; c < 4; ++c) {
      *(bf16x8*)&pat_hi[tid][c * 8] = ph[c];
      *(bf16x8*)&pat_lo[tid][c * 8] = pl[c];
    }
  }
  __syncthreads();   // pat + M + msqs ready

  // MFMA: wave w -> pixel half (w&1), l = l0 + (w>>1)
  const int pixhalf = w & 1;
  const int lsel = w >> 1;

  bf16x8 BH[4], BL[4];
  float xs4[4];
  #pragma unroll
  for (int j = 0; j < 4; ++j) {
    const int prow = (pixhalf << 6) + (j << 4) + (lane & 15);
    BH[j] = *(const bf16x8*)&pat_hi[prow][(lane >> 4) * 8];
    BL[j] = *(const bf16x8*)&pat_lo[prow][(lane >> 4) * 8];
    xs4[j] = xsq_s[prow];
  }

  const short* ah = &Mh[lsel][0][0] + (lane & 15) * 32 + ((lane >> 4) * 8);
  const short* al = &Ml[lsel][0][0] + (lane & 15) * 32 + ((lane >> 4) * 8);
  bf16x8 Ah[8], Al[8];
  #pragma unroll
  for (int t = 0; t < 8; ++t) {
    Ah[t] = *(const bf16x8*)(ah + t * 512);
    Al[t] = *(const bf16x8*)(al + t * 512);
  }

  const float ml = msqs[lsel];
  const f32x4 Z = {0.f, 0.f, 0.f, 0.f};
  float mx[4];
  #pragma unroll
  for (int j = 0; j < 4; ++j) mx[j] = -INFINITY;
  #pragma unroll
  for (int t = 0; t < 8; ++t) {
    #pragma unroll
    for (int j = 0; j < 4; ++j) {
      f32x4 C = __builtin_amdgcn_mfma_f32_16x16x32_bf16(Ah[t], BH[j], Z, 0, 0, 0);
      C = __builtin_amdgcn_mfma_f32_16x16x32_bf16(Al[t], BH[j], C, 0, 0, 0);
      C = __builtin_amdgcn_mfma_f32_16x16x32_bf16(Ah[t], BL[j], C, 0, 0, 0);
      if (t < 7) {
        mx[j] = fmaxf(mx[j], fmaxf(fmaxf(C[0], C[1]), fmaxf(C[2], C[3])));
      } else if (lane < 32) {   // tile 7: f-rows 112..119 valid, 120..127 pad
        mx[j] = fmaxf(mx[j], fmaxf(fmaxf(C[0], C[1]), fmaxf(C[2], C[3])));
      }
    }
  }

  const int l = l0 + lsel;
  #pragma unroll
  for (int j = 0; j < 4; ++j) {
    float m = mx[j];
    m = fmaxf(m, __shfl_xor(m, 16));
    m = fmaxf(m, __shfl_xor(m, 32));
    if (lane < 16) {
      // e = exp(-feature); feature = msq + xsq - 2*max >= 0 (min distance)
      const float e = expf(2.f * m - ml - xs4[j]);
      const int up = u0 + (pixhalf << 6) + (j << 4) + lane;
      const int pl = up / SS;
      const int sx = up - pl * SS;
      out[(((pl >> 1) * 16) + ((pl & 1) * 8) + l) * SS + sx] = e;
    }
  }
}

// k3: per-(b,c)-row sum + normalize (data already exp'd).
__global__ __launch_bounds__(1024) void k3_norm(float* __restrict__ data) {
  const int row = blockIdx.x;   // b*16 + c
  float* __restrict__ dr = data + row * SS;
  const int tid = threadIdx.x;
  float v[4];
  float sum = 0.f;
  #pragma unroll
  for (int i = 0; i < 4; ++i) {
    const int s = tid + i * 1024;
    const float f = (s < SS) ? dr[s] : 0.f;
    v[i] = f;
    sum += f;
  }
  #pragma unroll
  for (int off = 32; off >= 1; off >>= 1) sum += __shfl_xor(sum, off);
  __shared__ float red[16];
  if ((tid & 63) == 0) red[tid >> 6] = sum;
  __syncthreads();
  float tot = 0.f;
  #pragma unroll
  for (int i = 0; i < 16; ++i) tot += red[i];
  const float inv = 1.0f / tot;
  #pragma unroll
  for (int i = 0; i < 4; ++i) {
    const int s = tid + i * 1024;
    if (s < SS) dr[s] = v[i] * inv;
  }
}

extern "C" void kernel_launch(void* const* d_in, const int* in_sizes, int n_in,
                              void* d_out, int out_size, void* d_ws, size_t ws_size,
                              hipStream_t stream) {
  const float* x = (const float*)d_in[0];
  const float* kern = (const float*)d_in[1];
  float* out = (float*)d_out;
  hipLaunchKernelGGL(k12_feat, dim3(NBLK), dim3(256), 0, stream, x, kern, out);
  hipLaunchKernelGGL(k3_norm, dim3(128), dim3(1024), 0, stream, out);
}